// Round 3
// baseline (672.232 us; speedup 1.0000x reference)
//
#include <hip/hip_runtime.h>
#include <hip/hip_bf16.h>

#define Bn 128
#define Hd 512
#define Nn 1024

typedef __attribute__((ext_vector_type(8))) short short8;
typedef __attribute__((ext_vector_type(4))) float f32x4;

__device__ __forceinline__ float bf2f(unsigned u) {
    unsigned v = u << 16;
    float f;
    __builtin_memcpy(&f, &v, 4);
    return f;
}

__device__ __forceinline__ unsigned short f2bf(float f) {
    unsigned x;
    __builtin_memcpy(&x, &f, 4);
    unsigned r = x + 0x7fffu + ((x >> 16) & 1u);
    return (unsigned short)(r >> 16);
}

__device__ __forceinline__ float wave_sum(float v) {
    v += __shfl_xor(v, 32);
    v += __shfl_xor(v, 16);
    v += __shfl_xor(v, 8);
    v += __shfl_xor(v, 4);
    v += __shfl_xor(v, 2);
    v += __shfl_xor(v, 1);
    return v;
}

// tanh via v_exp + v_rcp (2.5ulp rcp -- negligible vs bf16 noise)
__device__ __forceinline__ float tanh_fast(float x) {
    float e = __expf(2.0f * x);
    return 1.0f - 2.0f * __builtin_amdgcn_rcpf(e + 1.0f);
}

// ---------------------------------------------------------------------------
// K0a: Wb[h][k] = bf16(attn_W[h][k]), k in [0,512)
// ---------------------------------------------------------------------------
__global__ void convert_W_kernel(const float* __restrict__ attn_W,
                                 unsigned short* __restrict__ Wb) {
    int idx = (blockIdx.x * 256 + threadIdx.x) * 8;
    int h = idx >> 9;
    int k = idx & 511;
    const float* p = attn_W + (size_t)h * 1024 + k;
    float4 v0 = *(const float4*)p;
    float4 v1 = *(const float4*)(p + 4);
    unsigned short t[8] = {f2bf(v0.x), f2bf(v0.y), f2bf(v0.z), f2bf(v0.w),
                           f2bf(v1.x), f2bf(v1.y), f2bf(v1.z), f2bf(v1.w)};
    *(uint4*)(Wb + idx) = *(uint4*)t;
}

// ---------------------------------------------------------------------------
// K0b: snT[b][n][k] = bf16(sn[b][k][n])  -- no-LDS transpose
// block: (b, kt, nt) covering 64k x 64n. thread t: n = t>>2, kp = t&3.
// reads: per j, 4 row-segments x 64 B (fully used); writes 32 B coalesced.
// ---------------------------------------------------------------------------
__global__ void transpose_sn_kernel(const float* __restrict__ sn,
                                    unsigned short* __restrict__ snT) {
    int bidx = blockIdx.x;              // 128 b * 8 kt * 16 nt
    int b = bidx >> 7;
    int kt = (bidx >> 4) & 7;
    int nt = bidx & 15;
    int k0 = kt << 6, n0 = nt << 6;
    int t = threadIdx.x;
    int n = t >> 2, kp = t & 3;
    const float* src = sn + ((size_t)(b * Hd) + k0 + kp * 16) * Nn + n0 + n;
    unsigned short tmp[16];
#pragma unroll
    for (int j = 0; j < 16; ++j) tmp[j] = f2bf(src[(size_t)j * Nn]);
    unsigned short* dst = snT + ((size_t)(b * Nn) + n0 + n) * Hd + k0 + kp * 16;
    *(uint4*)dst = *(uint4*)tmp;
    *(uint4*)(dst + 8) = *(uint4*)(tmp + 8);
}

// ---------------------------------------------------------------------------
// K1: mc_term[b,h] = sum_k attn_W[h, 512+k] * mc_hidden[b,k]   (fp32 exact)
// ---------------------------------------------------------------------------
__global__ void mc_term_kernel(const float* __restrict__ mc,
                               const float* __restrict__ attn_W,
                               float* __restrict__ mc_term) {
    int wg = (blockIdx.x * blockDim.x + threadIdx.x) >> 6;
    int lane = threadIdx.x & 63;
    int b = wg >> 9;
    int h = wg & 511;
    const float* m = mc + b * Hd + lane * 8;
    const float* w = attn_W + (size_t)h * 1024 + 512 + lane * 8;
    float4 m0 = *(const float4*)m, m1 = *(const float4*)(m + 4);
    float4 w0 = *(const float4*)w, w1 = *(const float4*)(w + 4);
    float acc = m0.x * w0.x + m0.y * w0.y + m0.z * w0.z + m0.w * w0.w +
                m1.x * w1.x + m1.y * w1.y + m1.z * w1.z + m1.w * w1.w;
    acc = wave_sum(acc);
    if (lane == 0) mc_term[b * Hd + h] = acc;
}

// ---------------------------------------------------------------------------
// K2: scores[b,n] -- barrier-free MFMA K-loop.
// WG = (b, 64-n tile); wave w: m0 = w*128 (mt=8), nt=4.
// A-frags straight from Wb (L2-hot), B-frags straight from snT (streamed).
// ---------------------------------------------------------------------------
__global__ __launch_bounds__(256, 2)
void attn_score_kernel(const unsigned short* __restrict__ snT,
                       const unsigned short* __restrict__ Wb,
                       const float* __restrict__ attn_v,
                       const float* __restrict__ mc_term,
                       float* __restrict__ scores) {
    __shared__ float av_s[512];
    __shared__ float mct_s[512];
    __shared__ float ssum[64];

    const int b = blockIdx.x >> 4;
    const int n0 = (blockIdx.x & 15) << 6;
    const int tid = threadIdx.x;
    const int lane = tid & 63;
    const int wid = tid >> 6;
    const int quad = lane >> 4;
    const int l15 = lane & 15;
    const int m0 = wid * 128;

    av_s[tid] = attn_v[tid];
    av_s[tid + 256] = attn_v[tid + 256];
    mct_s[tid] = mc_term[b * Hd + tid];
    mct_s[tid + 256] = mc_term[b * Hd + tid + 256];

    f32x4 acc[8][4];
#pragma unroll
    for (int i = 0; i < 8; ++i)
#pragma unroll
        for (int j = 0; j < 4; ++j) {
            f32x4 z = {0.f, 0.f, 0.f, 0.f};
            acc[i][j] = z;
        }

    const short* Abase = (const short*)Wb + (size_t)(m0 + l15) * Hd + quad * 8;
    const short* Bbase = (const short*)snT + ((size_t)(b * Nn) + n0 + l15) * Hd + quad * 8;

#pragma unroll 2
    for (int k0 = 0; k0 < 512; k0 += 32) {
        short8 bfr[4], aw[8];
#pragma unroll
        for (int nt = 0; nt < 4; ++nt)
            bfr[nt] = *(const short8*)(Bbase + (size_t)(nt * 16) * Hd + k0);
#pragma unroll
        for (int mt = 0; mt < 8; ++mt)
            aw[mt] = *(const short8*)(Abase + (size_t)(mt * 16) * Hd + k0);
#pragma unroll
        for (int mt = 0; mt < 8; ++mt)
#pragma unroll
            for (int nt = 0; nt < 4; ++nt)
                acc[mt][nt] = __builtin_amdgcn_mfma_f32_16x16x32_bf16(aw[mt], bfr[nt], acc[mt][nt], 0, 0, 0);
    }

    __syncthreads();   // av_s/mct_s visible; also before ssum init

    float s[4] = {0.f, 0.f, 0.f, 0.f};
#pragma unroll
    for (int mt = 0; mt < 8; ++mt) {
        int hb = m0 + mt * 16 + quad * 4;
#pragma unroll
        for (int r = 0; r < 4; ++r) {
            float av = av_s[hb + r];
            float mcv = mct_s[hb + r];
#pragma unroll
            for (int nt = 0; nt < 4; ++nt)
                s[nt] += av * tanh_fast(acc[mt][nt][r] + mcv);
        }
    }
    if (tid < 64) ssum[tid] = 0.f;
    __syncthreads();
#pragma unroll
    for (int nt = 0; nt < 4; ++nt) {
        float v = s[nt];
        v += __shfl_xor(v, 16);
        v += __shfl_xor(v, 32);
        if (lane < 16) atomicAdd(&ssum[nt * 16 + l15], v);
    }
    __syncthreads();
    if (tid < 64) scores[b * Nn + n0 + tid] = ssum[tid];
}

// ---------------------------------------------------------------------------
// K3: softmax over n per batch row (in-place)
// ---------------------------------------------------------------------------
__global__ void softmax_kernel(float* __restrict__ scores) {
    const int b = blockIdx.x;
    const int tid = threadIdx.x;
    const int lane = tid & 63, wid = tid >> 6;
    __shared__ float red[4];
    float v[4];
#pragma unroll
    for (int i = 0; i < 4; ++i) v[i] = scores[b * Nn + tid + i * 256];
    float m = fmaxf(fmaxf(v[0], v[1]), fmaxf(v[2], v[3]));
#pragma unroll
    for (int off = 32; off >= 1; off >>= 1) m = fmaxf(m, __shfl_xor(m, off));
    if (lane == 0) red[wid] = m;
    __syncthreads();
    m = fmaxf(fmaxf(red[0], red[1]), fmaxf(red[2], red[3]));
    __syncthreads();
    float s = 0.f;
#pragma unroll
    for (int i = 0; i < 4; ++i) {
        v[i] = __expf(v[i] - m);
        s += v[i];
    }
    s = wave_sum(s);
    if (lane == 0) red[wid] = s;
    __syncthreads();
    s = red[0] + red[1] + red[2] + red[3];
    float inv = __builtin_amdgcn_rcpf(s);
#pragma unroll
    for (int i = 0; i < 4; ++i) scores[b * Nn + tid + i * 256] = v[i] * inv;
}

// ---------------------------------------------------------------------------
// K4: context[b,h] += sum_n attns[b,n] * snT[b][n][h]
// block: (b, 128-n chunk); thread t owns h pair (2t,2t+1); coalesced row reads
// ---------------------------------------------------------------------------
__global__ void context_kernel(const unsigned short* __restrict__ snT,
                               const float* __restrict__ attns,
                               float* __restrict__ context) {
    int b = blockIdx.x >> 3;
    int nc = (blockIdx.x & 7) << 7;
    int t = threadIdx.x;
    __shared__ float a_s[128];
    if (t < 128) a_s[t] = attns[b * Nn + nc + t];
    __syncthreads();
    const unsigned short* base = snT + ((size_t)(b * Nn) + nc) * Hd + t * 2;
    float acc0 = 0.f, acc1 = 0.f;
#pragma unroll 4
    for (int i = 0; i < 128; ++i) {
        unsigned d = *(const unsigned*)(base + (size_t)i * Hd);
        float a = a_s[i];
        acc0 += a * bf2f(d & 0xffffu);
        acc1 += a * bf2f(d >> 16);
    }
    atomicAdd(&context[b * Hd + 2 * t], acc0);
    atomicAdd(&context[b * Hd + 2 * t + 1], acc1);
}

// ---------------------------------------------------------------------------
// K5: out1[b,h] = relu( dot([mc|context], fc1_W[h,:]) + fc1_b[h] )   (fp32)
// ---------------------------------------------------------------------------
__global__ void fc1_kernel(const float* __restrict__ mc,
                           const float* __restrict__ ctx,
                           const float* __restrict__ fc1_W,
                           const float* __restrict__ fc1_b,
                           float* __restrict__ out1) {
    int wg = (blockIdx.x * blockDim.x + threadIdx.x) >> 6;
    int lane = threadIdx.x & 63;
    int b = wg >> 9, h = wg & 511;
    const float* wr = fc1_W + (size_t)h * 1024;
    float acc = 0.f;
    {
        float4 w0 = *(const float4*)(wr + lane * 8);
        float4 w1 = *(const float4*)(wr + lane * 8 + 4);
        float4 x0 = *(const float4*)(mc + b * Hd + lane * 8);
        float4 x1 = *(const float4*)(mc + b * Hd + lane * 8 + 4);
        acc += w0.x * x0.x + w0.y * x0.y + w0.z * x0.z + w0.w * x0.w;
        acc += w1.x * x1.x + w1.y * x1.y + w1.z * x1.z + w1.w * x1.w;
    }
    {
        float4 w0 = *(const float4*)(wr + 512 + lane * 8);
        float4 w1 = *(const float4*)(wr + 512 + lane * 8 + 4);
        float4 x0 = *(const float4*)(ctx + b * Hd + lane * 8);
        float4 x1 = *(const float4*)(ctx + b * Hd + lane * 8 + 4);
        acc += w0.x * x0.x + w0.y * x0.y + w0.z * x0.z + w0.w * x0.w;
        acc += w1.x * x1.x + w1.y * x1.y + w1.z * x1.z + w1.w * x1.w;
    }
    acc = wave_sum(acc);
    if (lane == 0) out1[b * Hd + h] = fmaxf(acc + fc1_b[h], 0.f);
}

// ---------------------------------------------------------------------------
// K6: out2[b,h] = relu( dot(out1, fc2_W[h,:]) + fc2_b[h] )   (fp32)
// ---------------------------------------------------------------------------
__global__ void fc2_kernel(const float* __restrict__ out1,
                           const float* __restrict__ fc2_W,
                           const float* __restrict__ fc2_b,
                           float* __restrict__ out2) {
    int wg = (blockIdx.x * blockDim.x + threadIdx.x) >> 6;
    int lane = threadIdx.x & 63;
    int b = wg >> 9, h = wg & 511;
    const float* wr = fc2_W + (size_t)h * 512 + lane * 8;
    float4 w0 = *(const float4*)wr;
    float4 w1 = *(const float4*)(wr + 4);
    float4 x0 = *(const float4*)(out1 + b * Hd + lane * 8);
    float4 x1 = *(const float4*)(out1 + b * Hd + lane * 8 + 4);
    float acc = w0.x * x0.x + w0.y * x0.y + w0.z * x0.z + w0.w * x0.w +
                w1.x * x1.x + w1.y * x1.y + w1.z * x1.z + w1.w * x1.w;
    acc = wave_sum(acc);
    if (lane == 0) out2[b * Hd + h] = fmaxf(acc + fc2_b[h], 0.f);
}

// ---------------------------------------------------------------------------
// K7: probs[b,n] = sum_h ptr_v[h] * tanh( snT[b][n][h] + out2[b,h] )
// block: (b, 64-n tile); thread: n = t>>2, quad-part p = t&3 covers h subset
// h(p,j,i) = p*8 + j*32 + i ; quad shuffle-reduce at the end.
// ---------------------------------------------------------------------------
__global__ void final_kernel(const unsigned short* __restrict__ snT,
                             const float* __restrict__ ptr_v,
                             const float* __restrict__ out2,
                             float* __restrict__ probs) {
    int b = blockIdx.x >> 4;
    int n0 = (blockIdx.x & 15) << 6;
    int t = threadIdx.x;
    int n = n0 + (t >> 2), p = t & 3;
    __shared__ float pv_s[512], o2_s[512];
    pv_s[t] = ptr_v[t];
    pv_s[t + 256] = ptr_v[t + 256];
    o2_s[t] = out2[b * Hd + t];
    o2_s[t + 256] = out2[b * Hd + t + 256];
    __syncthreads();
    const unsigned short* row = snT + ((size_t)(b * Nn) + n) * Hd + p * 8;
    float a = 0.f;
#pragma unroll 4
    for (int j = 0; j < 16; ++j) {
        uint4 d = *(const uint4*)(row + j * 32);
        int hb = p * 8 + j * 32;
        const unsigned* u = (const unsigned*)&d;
#pragma unroll
        for (int q = 0; q < 4; ++q) {
            int h = hb + q * 2;
            float x0 = bf2f(u[q] & 0xffffu);
            float x1 = bf2f(u[q] >> 16);
            a += pv_s[h] * tanh_fast(x0 + o2_s[h]);
            a += pv_s[h + 1] * tanh_fast(x1 + o2_s[h + 1]);
        }
    }
    a += __shfl_xor(a, 1);
    a += __shfl_xor(a, 2);
    if (p == 0) probs[b * Nn + n] = a;
}

// ---------------------------------------------------------------------------
extern "C" void kernel_launch(void* const* d_in, const int* in_sizes, int n_in,
                              void* d_out, int out_size, void* d_ws, size_t ws_size,
                              hipStream_t stream) {
    const float* mc  = (const float*)d_in[0];
    const float* sn  = (const float*)d_in[1];
    const float* aW  = (const float*)d_in[2];
    const float* av  = (const float*)d_in[3];
    const float* pv  = (const float*)d_in[4];
    const float* f1W = (const float*)d_in[5];
    const float* f1b = (const float*)d_in[6];
    const float* f2W = (const float*)d_in[7];
    const float* f2b = (const float*)d_in[8];

    unsigned short* snT = (unsigned short*)d_ws;            // 128 MB
    unsigned short* Wb  = snT + (size_t)Bn * Nn * Hd;       // 512 KB
    float* fws     = (float*)(Wb + 512 * 512);
    float* mc_term = fws;                                   // 256 KB
    float* scores  = mc_term + Bn * Hd;                     // 512 KB
    float* context = scores + Bn * Nn;                      // 256 KB
    float* out1    = context + Bn * Hd;                     // 256 KB
    float* out2    = out1 + Bn * Hd;                        // 256 KB
    float* probs   = (float*)d_out;

    hipMemsetAsync(context, 0, Bn * Hd * sizeof(float), stream);
    convert_W_kernel<<<dim3(128), dim3(256), 0, stream>>>(aW, Wb);
    transpose_sn_kernel<<<dim3(16384), dim3(256), 0, stream>>>(sn, snT);
    mc_term_kernel<<<dim3(16384), dim3(256), 0, stream>>>(mc, aW, mc_term);
    attn_score_kernel<<<dim3(2048), dim3(256), 0, stream>>>(snT, Wb, av, mc_term, scores);
    softmax_kernel<<<dim3(128), dim3(256), 0, stream>>>(scores);
    context_kernel<<<dim3(1024), dim3(256), 0, stream>>>(snT, scores, context);
    fc1_kernel<<<dim3(16384), dim3(256), 0, stream>>>(mc, context, f1W, f1b, out1);
    fc2_kernel<<<dim3(16384), dim3(256), 0, stream>>>(out1, f2W, f2b, out2);
    final_kernel<<<dim3(2048), dim3(256), 0, stream>>>(snT, pv, out2, probs);
}

// Round 4
// 565.764 us; speedup vs baseline: 1.1882x; 1.1882x over previous
//
#include <hip/hip_runtime.h>
#include <hip/hip_bf16.h>

#define Bn 128
#define Hd 512
#define Nn 1024

typedef __attribute__((ext_vector_type(8))) short short8;
typedef __attribute__((ext_vector_type(4))) float f32x4;

#define GLOAD_LDS16(gptr, lptr)                                                     \
    __builtin_amdgcn_global_load_lds(                                               \
        (const __attribute__((address_space(1))) void*)(gptr),                      \
        (__attribute__((address_space(3))) void*)(lptr), 16, 0, 0)

__device__ __forceinline__ float bf2f(unsigned u) {
    unsigned v = u << 16;
    float f;
    __builtin_memcpy(&f, &v, 4);
    return f;
}

__device__ __forceinline__ unsigned short f2bf(float f) {
    unsigned x;
    __builtin_memcpy(&x, &f, 4);
    unsigned r = x + 0x7fffu + ((x >> 16) & 1u);
    return (unsigned short)(r >> 16);
}

__device__ __forceinline__ float wave_sum(float v) {
    v += __shfl_xor(v, 32);
    v += __shfl_xor(v, 16);
    v += __shfl_xor(v, 8);
    v += __shfl_xor(v, 4);
    v += __shfl_xor(v, 2);
    v += __shfl_xor(v, 1);
    return v;
}

__device__ __forceinline__ float tanh_fast(float x) {
    float e = __expf(2.0f * x);
    return 1.0f - 2.0f * __builtin_amdgcn_rcpf(e + 1.0f);
}

// ---------------------------------------------------------------------------
// K0a: Wb[h][k] = bf16(attn_W[h][k]), k in [0,512)
// ---------------------------------------------------------------------------
__global__ void convert_W_kernel(const float* __restrict__ attn_W,
                                 unsigned short* __restrict__ Wb) {
    int idx = (blockIdx.x * 256 + threadIdx.x) * 8;
    int h = idx >> 9;
    int k = idx & 511;
    const float* p = attn_W + (size_t)h * 1024 + k;
    float4 v0 = *(const float4*)p;
    float4 v1 = *(const float4*)(p + 4);
    unsigned short t[8] = {f2bf(v0.x), f2bf(v0.y), f2bf(v0.z), f2bf(v0.w),
                           f2bf(v1.x), f2bf(v1.y), f2bf(v1.z), f2bf(v1.w)};
    *(uint4*)(Wb + idx) = *(uint4*)t;
}

// ---------------------------------------------------------------------------
// K0b: snT[b][n][k] = bf16(sn[b][k][n]) -- LDS transpose, coalesced both sides
// block tile: 64 k x 128 n. LDS u32 [32 kpair][132] (k,k+1 packed per u32).
// ---------------------------------------------------------------------------
__global__ void transpose_sn_kernel(const float* __restrict__ sn,
                                    unsigned short* __restrict__ snT) {
    __shared__ unsigned ldsb[32 * 132];
    int bid = blockIdx.x;                 // 128 b * 8 kt * 8 nt
    int b = bid >> 6;
    int kt = (bid >> 3) & 7;
    int nt = bid & 7;
    int k0 = kt << 6, n0 = nt << 7;
    int t = threadIdx.x;

    // phase 1: coalesced fp32 reads (512B per row-group), pack k-pairs, LDS
    int kp_l = t >> 5;                    // 0..7
    int n4 = (t & 31) * 4;
#pragma unroll
    for (int j = 0; j < 4; ++j) {
        int kp = j * 8 + kp_l;            // 0..31
        const float* p0 = sn + ((size_t)(b * Hd + k0 + 2 * kp)) * Nn + n0 + n4;
        float4 f0 = *(const float4*)p0;
        float4 f1 = *(const float4*)(p0 + Nn);
        unsigned u[4];
        u[0] = (unsigned)f2bf(f0.x) | ((unsigned)f2bf(f1.x) << 16);
        u[1] = (unsigned)f2bf(f0.y) | ((unsigned)f2bf(f1.y) << 16);
        u[2] = (unsigned)f2bf(f0.z) | ((unsigned)f2bf(f1.z) << 16);
        u[3] = (unsigned)f2bf(f0.w) | ((unsigned)f2bf(f1.w) << 16);
        *(uint4*)&ldsb[kp * 132 + n4] = *(uint4*)u;
    }
    __syncthreads();

    // phase 2: gather k-contiguous 64B per (n, chunk), coalesced 16B stores
    int c = t & 7;                        // chunk: k-offset c*8 .. c*8+7
#pragma unroll
    for (int it = 0; it < 4; ++it) {
        int n = (t >> 3) + it * 32;
        unsigned u[4];
#pragma unroll
        for (int i = 0; i < 4; ++i) u[i] = ldsb[(c * 4 + i) * 132 + n];
        unsigned short* dst = snT + ((size_t)(b * Nn) + n0 + n) * Hd + k0 + c * 8;
        *(uint4*)dst = *(uint4*)u;
    }
}

// ---------------------------------------------------------------------------
// K1: mc_term[b,h] = sum_k attn_W[h, 512+k] * mc_hidden[b,k]   (fp32 exact)
// ---------------------------------------------------------------------------
__global__ void mc_term_kernel(const float* __restrict__ mc,
                               const float* __restrict__ attn_W,
                               float* __restrict__ mc_term) {
    int wg = (blockIdx.x * blockDim.x + threadIdx.x) >> 6;
    int lane = threadIdx.x & 63;
    int b = wg >> 9;
    int h = wg & 511;
    const float* m = mc + b * Hd + lane * 8;
    const float* w = attn_W + (size_t)h * 1024 + 512 + lane * 8;
    float4 m0 = *(const float4*)m, m1 = *(const float4*)(m + 4);
    float4 w0 = *(const float4*)w, w1 = *(const float4*)(w + 4);
    float acc = m0.x * w0.x + m0.y * w0.y + m0.z * w0.z + m0.w * w0.w +
                m1.x * w1.x + m1.y * w1.y + m1.z * w1.z + m1.w * w1.w;
    acc = wave_sum(acc);
    if (lane == 0) mc_term[b * Hd + h] = acc;
}

// ---------------------------------------------------------------------------
// K2: scores[b,n] -- m97-style LDS-staged MFMA GEMM.
// WG = (b, 64-n tile); wave w owns m-rows [w*128, w*128+128). BK=64, K=512.
// global_load_lds width 16 with XOR chunk swizzle (conflict-free ds_read_b128).
// ---------------------------------------------------------------------------
__global__ __launch_bounds__(256, 2)
void attn_score_kernel(const unsigned short* __restrict__ snT,
                       const unsigned short* __restrict__ Wb,
                       const float* __restrict__ attn_v,
                       const float* __restrict__ mc_term,
                       float* __restrict__ scores) {
    __shared__ __align__(16) unsigned short A_lds[512 * 64];  // [m][k] 64KB
    __shared__ __align__(16) unsigned short B_lds[64 * 64];   // [n][k] 8KB
    __shared__ float av_s[512];
    __shared__ float mct_s[512];
    __shared__ float ssum[64];

    const int b = blockIdx.x >> 4;
    const int n0 = (blockIdx.x & 15) << 6;
    const int tid = threadIdx.x;
    const int lane = tid & 63;
    const int wid = tid >> 6;
    const int quad = lane >> 4;
    const int l15 = lane & 15;
    const int m0 = wid * 128;

    av_s[tid] = attn_v[tid];
    av_s[tid + 256] = attn_v[tid + 256];
    mct_s[tid] = mc_term[b * Hd + tid];
    mct_s[tid + 256] = mc_term[b * Hd + tid + 256];
    if (tid < 64) ssum[tid] = 0.f;

    f32x4 acc[8][4];
#pragma unroll
    for (int i = 0; i < 8; ++i)
#pragma unroll
        for (int j = 0; j < 4; ++j) {
            f32x4 z = {0.f, 0.f, 0.f, 0.f};
            acc[i][j] = z;
        }

    const int r8 = lane >> 3;                  // row within 8-row staging group
    const int csw = ((lane & 7) ^ r8) * 16;    // swizzled chunk byte offset
    const char* Wg = (const char*)Wb;          // row stride 1024 B
    const char* Bg = (const char*)snT + ((size_t)(b * Nn + n0)) * 1024;
    const int key = l15 & 7;

    for (int k0 = 0; k0 < 512; k0 += 64) {
        // stage A: this wave's 128 m-rows, 16 instrs x 1KB
#pragma unroll
        for (int i = 0; i < 16; ++i) {
            const int row = m0 + i * 8;
            GLOAD_LDS16(Wg + (size_t)(row + r8) * 1024 + k0 * 2 + csw,
                        (char*)A_lds + row * 128);
        }
        // stage B: wave's 16 n-rows, 2 instrs
#pragma unroll
        for (int i = 0; i < 2; ++i) {
            const int row = wid * 16 + i * 8;
            GLOAD_LDS16(Bg + (size_t)(row + r8) * 1024 + k0 * 2 + csw,
                        (char*)B_lds + row * 128);
        }
        __syncthreads();
#pragma unroll
        for (int kk = 0; kk < 2; ++kk) {
            const int cb = quad + kk * 4;
            short8 bfr[4], afr[8];
#pragma unroll
            for (int nt = 0; nt < 4; ++nt) {
                const int n = nt * 16 + l15;
                bfr[nt] = *(const short8*)((const char*)B_lds + n * 128 + ((cb ^ key) * 16));
            }
#pragma unroll
            for (int mt = 0; mt < 8; ++mt) {
                const int m = m0 + mt * 16 + l15;
                afr[mt] = *(const short8*)((const char*)A_lds + m * 128 + ((cb ^ key) * 16));
            }
#pragma unroll
            for (int mt = 0; mt < 8; ++mt)
#pragma unroll
                for (int nt = 0; nt < 4; ++nt)
                    acc[mt][nt] = __builtin_amdgcn_mfma_f32_16x16x32_bf16(afr[mt], bfr[nt], acc[mt][nt], 0, 0, 0);
        }
        __syncthreads();
    }

    // epilogue: tanh + attn_v dot, reduce over h
    float s[4] = {0.f, 0.f, 0.f, 0.f};
#pragma unroll
    for (int mt = 0; mt < 8; ++mt) {
        int hb = m0 + mt * 16 + quad * 4;
#pragma unroll
        for (int r = 0; r < 4; ++r) {
            float av = av_s[hb + r];
            float mcv = mct_s[hb + r];
#pragma unroll
            for (int nt = 0; nt < 4; ++nt)
                s[nt] += av * tanh_fast(acc[mt][nt][r] + mcv);
        }
    }
#pragma unroll
    for (int nt = 0; nt < 4; ++nt) {
        float v = s[nt];
        v += __shfl_xor(v, 16);
        v += __shfl_xor(v, 32);
        if (lane < 16) atomicAdd(&ssum[nt * 16 + l15], v);
    }
    __syncthreads();
    if (tid < 64) scores[b * Nn + n0 + tid] = ssum[tid];
}

// ---------------------------------------------------------------------------
// K3: softmax over n per batch row (in-place)
// ---------------------------------------------------------------------------
__global__ void softmax_kernel(float* __restrict__ scores) {
    const int b = blockIdx.x;
    const int tid = threadIdx.x;
    const int lane = tid & 63, wid = tid >> 6;
    __shared__ float red[4];
    float v[4];
#pragma unroll
    for (int i = 0; i < 4; ++i) v[i] = scores[b * Nn + tid + i * 256];
    float m = fmaxf(fmaxf(v[0], v[1]), fmaxf(v[2], v[3]));
#pragma unroll
    for (int off = 32; off >= 1; off >>= 1) m = fmaxf(m, __shfl_xor(m, off));
    if (lane == 0) red[wid] = m;
    __syncthreads();
    m = fmaxf(fmaxf(red[0], red[1]), fmaxf(red[2], red[3]));
    __syncthreads();
    float s = 0.f;
#pragma unroll
    for (int i = 0; i < 4; ++i) {
        v[i] = __expf(v[i] - m);
        s += v[i];
    }
    s = wave_sum(s);
    if (lane == 0) red[wid] = s;
    __syncthreads();
    s = red[0] + red[1] + red[2] + red[3];
    float inv = __builtin_amdgcn_rcpf(s);
#pragma unroll
    for (int i = 0; i < 4; ++i) scores[b * Nn + tid + i * 256] = v[i] * inv;
}

// ---------------------------------------------------------------------------
// K4: context[b,h] += sum_n attns[b,n] * snT[b][n][h-pair]
// ---------------------------------------------------------------------------
__global__ void context_kernel(const unsigned short* __restrict__ snT,
                               const float* __restrict__ attns,
                               float* __restrict__ context) {
    int b = blockIdx.x >> 3;
    int nc = (blockIdx.x & 7) << 7;
    int t = threadIdx.x;
    __shared__ float a_s[128];
    if (t < 128) a_s[t] = attns[b * Nn + nc + t];
    __syncthreads();
    const unsigned short* base = snT + ((size_t)(b * Nn) + nc) * Hd + t * 2;
    float acc0 = 0.f, acc1 = 0.f;
#pragma unroll 4
    for (int i = 0; i < 128; ++i) {
        unsigned d = *(const unsigned*)(base + (size_t)i * Hd);
        float a = a_s[i];
        acc0 += a * bf2f(d & 0xffffu);
        acc1 += a * bf2f(d >> 16);
    }
    atomicAdd(&context[b * Hd + 2 * t], acc0);
    atomicAdd(&context[b * Hd + 2 * t + 1], acc1);
}

// ---------------------------------------------------------------------------
// K5: out1[b,h] = relu( dot([mc|context], fc1_W[h,:]) + fc1_b[h] )   (fp32)
// ---------------------------------------------------------------------------
__global__ void fc1_kernel(const float* __restrict__ mc,
                           const float* __restrict__ ctx,
                           const float* __restrict__ fc1_W,
                           const float* __restrict__ fc1_b,
                           float* __restrict__ out1) {
    int wg = (blockIdx.x * blockDim.x + threadIdx.x) >> 6;
    int lane = threadIdx.x & 63;
    int b = wg >> 9, h = wg & 511;
    const float* wr = fc1_W + (size_t)h * 1024;
    float acc = 0.f;
    {
        float4 w0 = *(const float4*)(wr + lane * 8);
        float4 w1 = *(const float4*)(wr + lane * 8 + 4);
        float4 x0 = *(const float4*)(mc + b * Hd + lane * 8);
        float4 x1 = *(const float4*)(mc + b * Hd + lane * 8 + 4);
        acc += w0.x * x0.x + w0.y * x0.y + w0.z * x0.z + w0.w * x0.w;
        acc += w1.x * x1.x + w1.y * x1.y + w1.z * x1.z + w1.w * x1.w;
    }
    {
        float4 w0 = *(const float4*)(wr + 512 + lane * 8);
        float4 w1 = *(const float4*)(wr + 512 + lane * 8 + 4);
        float4 x0 = *(const float4*)(ctx + b * Hd + lane * 8);
        float4 x1 = *(const float4*)(ctx + b * Hd + lane * 8 + 4);
        acc += w0.x * x0.x + w0.y * x0.y + w0.z * x0.z + w0.w * x0.w;
        acc += w1.x * x1.x + w1.y * x1.y + w1.z * x1.z + w1.w * x1.w;
    }
    acc = wave_sum(acc);
    if (lane == 0) out1[b * Hd + h] = fmaxf(acc + fc1_b[h], 0.f);
}

// ---------------------------------------------------------------------------
// K6: out2[b,h] = relu( dot(out1, fc2_W[h,:]) + fc2_b[h] )   (fp32)
// ---------------------------------------------------------------------------
__global__ void fc2_kernel(const float* __restrict__ out1,
                           const float* __restrict__ fc2_W,
                           const float* __restrict__ fc2_b,
                           float* __restrict__ out2) {
    int wg = (blockIdx.x * blockDim.x + threadIdx.x) >> 6;
    int lane = threadIdx.x & 63;
    int b = wg >> 9, h = wg & 511;
    const float* wr = fc2_W + (size_t)h * 512 + lane * 8;
    float4 w0 = *(const float4*)wr;
    float4 w1 = *(const float4*)(wr + 4);
    float4 x0 = *(const float4*)(out1 + b * Hd + lane * 8);
    float4 x1 = *(const float4*)(out1 + b * Hd + lane * 8 + 4);
    float acc = w0.x * x0.x + w0.y * x0.y + w0.z * x0.z + w0.w * x0.w +
                w1.x * x1.x + w1.y * x1.y + w1.z * x1.z + w1.w * x1.w;
    acc = wave_sum(acc);
    if (lane == 0) out2[b * Hd + h] = fmaxf(acc + fc2_b[h], 0.f);
}

// ---------------------------------------------------------------------------
// K7: probs[b,n] = sum_h ptr_v[h] * tanh( snT[b][n][h] + out2[b,h] )
// ---------------------------------------------------------------------------
__global__ void final_kernel(const unsigned short* __restrict__ snT,
                             const float* __restrict__ ptr_v,
                             const float* __restrict__ out2,
                             float* __restrict__ probs) {
    int b = blockIdx.x >> 4;
    int n0 = (blockIdx.x & 15) << 6;
    int t = threadIdx.x;
    int n = n0 + (t >> 2), p = t & 3;
    __shared__ float pv_s[512], o2_s[512];
    pv_s[t] = ptr_v[t];
    pv_s[t + 256] = ptr_v[t + 256];
    o2_s[t] = out2[b * Hd + t];
    o2_s[t + 256] = out2[b * Hd + t + 256];
    __syncthreads();
    const unsigned short* row = snT + ((size_t)(b * Nn) + n) * Hd + p * 8;
    float a = 0.f;
#pragma unroll 4
    for (int j = 0; j < 16; ++j) {
        uint4 d = *(const uint4*)(row + j * 32);
        int hb = p * 8 + j * 32;
        const unsigned* u = (const unsigned*)&d;
#pragma unroll
        for (int q = 0; q < 4; ++q) {
            int h = hb + q * 2;
            float x0 = bf2f(u[q] & 0xffffu);
            float x1 = bf2f(u[q] >> 16);
            a += pv_s[h] * tanh_fast(x0 + o2_s[h]);
            a += pv_s[h + 1] * tanh_fast(x1 + o2_s[h + 1]);
        }
    }
    a += __shfl_xor(a, 1);
    a += __shfl_xor(a, 2);
    if (p == 0) probs[b * Nn + n] = a;
}

// ---------------------------------------------------------------------------
extern "C" void kernel_launch(void* const* d_in, const int* in_sizes, int n_in,
                              void* d_out, int out_size, void* d_ws, size_t ws_size,
                              hipStream_t stream) {
    const float* mc  = (const float*)d_in[0];
    const float* sn  = (const float*)d_in[1];
    const float* aW  = (const float*)d_in[2];
    const float* av  = (const float*)d_in[3];
    const float* pv  = (const float*)d_in[4];
    const float* f1W = (const float*)d_in[5];
    const float* f1b = (const float*)d_in[6];
    const float* f2W = (const float*)d_in[7];
    const float* f2b = (const float*)d_in[8];

    unsigned short* snT = (unsigned short*)d_ws;            // 128 MB
    unsigned short* Wb  = snT + (size_t)Bn * Nn * Hd;       // 512 KB
    float* fws     = (float*)(Wb + 512 * 512);
    float* mc_term = fws;
    float* scores  = mc_term + Bn * Hd;
    float* context = scores + Bn * Nn;
    float* out1    = context + Bn * Hd;
    float* out2    = out1 + Bn * Hd;
    float* probs   = (float*)d_out;

    hipMemsetAsync(context, 0, Bn * Hd * sizeof(float), stream);
    convert_W_kernel<<<dim3(128), dim3(256), 0, stream>>>(aW, Wb);
    transpose_sn_kernel<<<dim3(8192), dim3(256), 0, stream>>>(sn, snT);
    mc_term_kernel<<<dim3(16384), dim3(256), 0, stream>>>(mc, aW, mc_term);
    attn_score_kernel<<<dim3(2048), dim3(256), 0, stream>>>(snT, Wb, av, mc_term, scores);
    softmax_kernel<<<dim3(128), dim3(256), 0, stream>>>(scores);
    context_kernel<<<dim3(1024), dim3(256), 0, stream>>>(snT, scores, context);
    fc1_kernel<<<dim3(16384), dim3(256), 0, stream>>>(mc, context, f1W, f1b, out1);
    fc2_kernel<<<dim3(16384), dim3(256), 0, stream>>>(out1, f2W, f2b, out2);
    final_kernel<<<dim3(2048), dim3(256), 0, stream>>>(snT, pv, out2, probs);
}